// Round 18
// baseline (40.586 us; speedup 1.0000x reference)
//
#include <hip/hip_runtime.h>

// KNN (k=16) within batch-diagonal blocks + neighbor-feature mean-pool.
// N = 16384 points, 8 batches of 2048 (contiguous), FEAT = 16.
//
// R17 -> R18: second half of the scan no longer computes exact d2.
//  * thr = 16th-smallest of the 64 FIRST-HALF lane-mins (min over 16
//    disjoint candidates each => 16 distinct candidates <= thr => valid).
//    Phase A's t=16..31 exact pass is deleted (~144 instrs/wave).
//  * Phase B t=16..31 uses R5's conservative test: dot >= fma(qs,0.5,C),
//    C = (x2s-thr)*0.5 - 0.03 (margin >> rounding discrepancy => superset
//    of exact pass => no true top-16 lost). Extras are filtered by Phase
//    C's exact recomputed keys: kv = 16th-smallest survivor key = true
//    16th-best, since all true top-16 survive. Slot order remains globally
//    ascending in candidate index (part1 < part2), so tie logic unchanged.
//  * E[S] grows ~18 -> ~36; fast path still S <= 64 almost always; rare
//    overflow waves take the proven chunked u64 sort path.
//
// Exactness machinery otherwise unchanged (16 passing rounds):
// reference-bit d2 (ascending-k FMA chain, rounded squares, (x2+y2)-2*dot),
// u32/u64 mono keys, ballot append in index order, exact top-16 SET via
// key sort + stable ties, butterfly mean (rounding-only relaxation).

typedef unsigned long long u64;
typedef unsigned int u32;

#define FEAT 16
#define BLK_WAVES 8
#define THREADS (BLK_WAVES * 64)   // 512
#define LIST_CAP 512
#define INF_KEY 0xFFFFFFFFFFFFFFFFull

__global__ void knn_prep(const float* __restrict__ y, float4* __restrict__ yp, int m)
{
    const int j = blockIdx.x * 256 + (int)threadIdx.x;
    if (j < m) {
        const float a0 = y[(size_t)j * 3 + 0];
        const float a1 = y[(size_t)j * 3 + 1];
        const float a2 = y[(size_t)j * 3 + 2];
        const float s  = __fadd_rn(__fadd_rn(__fmul_rn(a0, a0), __fmul_rn(a1, a1)),
                                   __fmul_rn(a2, a2));
        yp[j] = make_float4(a0, a1, a2, s);
    }
}

__device__ __forceinline__ u32 mono(float f) {
    const u32 b = __float_as_uint(f);
    return b ^ (((u32)(((int)b) >> 31)) | 0x80000000u);
}
__device__ __forceinline__ float unmono(u32 h) {
    const u32 b = (h & 0x80000000u) ? (h & 0x7FFFFFFFu) : ~h;
    return __uint_as_float(b);
}
__device__ __forceinline__ int lanes_below(u64 mask) {
    return __builtin_amdgcn_mbcnt_hi((u32)(mask >> 32),
           __builtin_amdgcn_mbcnt_lo((u32)mask, 0));
}

// Cross-lane bitonic sort over the 64 lanes, ascending by lane index.
__device__ __forceinline__ u32 sort64_u32(u32 k, int lane) {
#pragma unroll
    for (int kk = 2; kk <= 64; kk <<= 1) {
#pragma unroll
        for (int j = kk >> 1; j > 0; j >>= 1) {
            const u32 o = __shfl_xor(k, j);
            const bool keep_min = (((lane & j) == 0) == ((lane & kk) == 0));
            const u32 mn = (k < o) ? k : o;
            const u32 mx = (k < o) ? o : k;
            k = keep_min ? mn : mx;
        }
    }
    return k;
}
__device__ __forceinline__ u64 sort64_u64(u64 k, int lane) {
#pragma unroll
    for (int kk = 2; kk <= 64; kk <<= 1) {
#pragma unroll
        for (int j = kk >> 1; j > 0; j >>= 1) {
            const u64 o = __shfl_xor(k, j);
            const bool keep_min = (((lane & j) == 0) == ((lane & kk) == 0));
            const u64 mn = (k < o) ? k : o;
            const u64 mx = (k < o) ? o : k;
            k = keep_min ? mn : mx;
        }
    }
    return k;
}

// REGC: leading iterations with register-cached exact d2 (FULL unroll);
// these also seed thr. TOTC > 0: compile-time candidate count. 0: fallback.
template <int TOTC, int REGC>
__global__ __launch_bounds__(THREADS, 8) void knn_main(
    const float* __restrict__ x, const float4* __restrict__ yp,
    const float* __restrict__ y, const float* __restrict__ feat,
    const int* __restrict__ x_batch, float* __restrict__ out,
    int n, int per, int packed)
{
    __shared__ u32 list_s[BLK_WAVES][LIST_CAP];  // 16 KiB survivor indices
    __shared__ u32 rank_s[BLK_WAVES][16];        // 512 B winner indices

    const int lane = (int)threadIdx.x & 63;
    const int wv   = (int)(threadIdx.x >> 6);
    const int i    = blockIdx.x * BLK_WAVES + wv;   // this wave's point
    if (i >= n) return;

    const int b     = x_batch[i];                   // lane-uniform
    const int ybase = b * per;

    const float px0 = x[(size_t)i * 3 + 0];
    const float px1 = x[(size_t)i * 3 + 1];
    const float px2 = x[(size_t)i * 3 + 2];
    const float x2s = __fadd_rn(__fadd_rn(__fmul_rn(px0, px0), __fmul_rn(px1, px1)),
                                __fmul_rn(px2, px2));

    float thrf;
    int S = 0;                                      // wave-uniform count

    if constexpr (TOTC > 0) {
        // ---- Phase A (first half only): exact d2, cached + lane-min.
        float d2c[REGC];
        float md0 = __builtin_inff(), md1 = __builtin_inff();
#pragma unroll
        for (int t = 0; t < REGC; ++t) {
            const float4 q = yp[ybase + t * 64 + lane];   // coalesced
            float dot = __fmaf_rn(px0, q.x, 0.0f);
            dot = __fmaf_rn(px1, q.y, dot);
            dot = __fmaf_rn(px2, q.z, dot);
            const float d2 = __fsub_rn(__fadd_rn(x2s, q.w), __fmul_rn(2.0f, dot));
            d2c[t] = d2;
            if (t & 1) md1 = fminf(md1, d2); else md0 = fminf(md0, d2);
        }
        const float md = fminf(md0, md1);

        // thr = 16th-smallest of the 64 first-half lane-mins (exact bits).
        // Valid: those are mins over 64 disjoint 16-candidate sets => the 16
        // smallest are 16 distinct candidates <= thr.
        const u32 sorted = sort64_u32(mono(md), lane);
        thrf = unmono(__shfl(sorted, 15));

        // Conservative-test constant for the second half (margin 0.03 >>
        // rounding discrepancy of the rearrangement => superset of exact).
        const float Cm = (x2s - thrf) * 0.5f - 0.03f;

        // ---- Phase B1: cached exact test, ballot append (index order).
#pragma unroll
        for (int t = 0; t < REGC; ++t) {
            const bool pred = (d2c[t] <= thrf);
            const u64 mask = __ballot(pred);
            if (pred) {
                const int slot = S + lanes_below(mask);
                if (slot < LIST_CAP)
                    list_s[wv][slot] = (u32)(ybase + t * 64 + lane);
            }
            S += __popcll(mask);
        }
        // ---- Phase B2: conservative test only (no exact d2 needed).
#pragma unroll 4
        for (int t = REGC; t < TOTC; ++t) {
            const float4 q = yp[ybase + t * 64 + lane];
            float dot = __fmaf_rn(px0, q.x, 0.0f);
            dot = __fmaf_rn(px1, q.y, dot);
            dot = __fmaf_rn(px2, q.z, dot);
            const bool pred = (dot >= __fmaf_rn(q.w, 0.5f, Cm));
            const u64 mask = __ballot(pred);
            if (pred) {
                const int slot = S + lanes_below(mask);
                if (slot < LIST_CAP)
                    list_s[wv][slot] = (u32)(ybase + t * 64 + lane);
            }
            S += __popcll(mask);
        }
    } else {
        // Generic fallback: exact two-pass scan (R8 structure, unpacked ok).
        const int iters = per / 64;
        float md = __builtin_inff();
        for (int t = 0; t < iters; ++t) {
            const int j = ybase + t * 64 + lane;
            float q0, q1, q2, qs;
            if (packed) {
                const float4 q = yp[j];
                q0 = q.x; q1 = q.y; q2 = q.z; qs = q.w;
            } else {
                q0 = y[(size_t)j * 3 + 0];
                q1 = y[(size_t)j * 3 + 1];
                q2 = y[(size_t)j * 3 + 2];
                qs = __fadd_rn(__fadd_rn(__fmul_rn(q0, q0), __fmul_rn(q1, q1)),
                               __fmul_rn(q2, q2));
            }
            float dot = __fmaf_rn(px0, q0, 0.0f);
            dot = __fmaf_rn(px1, q1, dot);
            dot = __fmaf_rn(px2, q2, dot);
            md = fminf(md, __fsub_rn(__fadd_rn(x2s, qs), __fmul_rn(2.0f, dot)));
        }
        const u32 sorted = sort64_u32(mono(md), lane);
        thrf = unmono(__shfl(sorted, 15));
        for (int t = 0; t < iters; ++t) {
            const int j = ybase + t * 64 + lane;
            float q0, q1, q2, qs;
            if (packed) {
                const float4 q = yp[j];
                q0 = q.x; q1 = q.y; q2 = q.z; qs = q.w;
            } else {
                q0 = y[(size_t)j * 3 + 0];
                q1 = y[(size_t)j * 3 + 1];
                q2 = y[(size_t)j * 3 + 2];
                qs = __fadd_rn(__fadd_rn(__fmul_rn(q0, q0), __fmul_rn(q1, q1)),
                               __fmul_rn(q2, q2));
            }
            float dot = __fmaf_rn(px0, q0, 0.0f);
            dot = __fmaf_rn(px1, q1, dot);
            dot = __fmaf_rn(px2, q2, dot);
            const float d2 = __fsub_rn(__fadd_rn(x2s, qs), __fmul_rn(2.0f, dot));
            const bool pred = (d2 <= thrf);
            const u64 mask = __ballot(pred);
            if (pred) {
                const int slot = S + lanes_below(mask);
                if (slot < LIST_CAP)
                    list_s[wv][slot] = (u32)j;
            }
            S += __popcll(mask);
        }
    }

    if (S > LIST_CAP) S = LIST_CAP;

    // Exact d2 bits from index (IDENTICAL op sequence/inputs as Phase A).
    auto key32_of = [&](u32 idx) -> u32 {
        const float4 q = packed ? yp[idx]
                                : make_float4(y[(size_t)idx * 3 + 0],
                                              y[(size_t)idx * 3 + 1],
                                              y[(size_t)idx * 3 + 2], 0.0f);
        float qs;
        if (packed) qs = q.w;
        else        qs = __fadd_rn(__fadd_rn(__fmul_rn(q.x, q.x), __fmul_rn(q.y, q.y)),
                                   __fmul_rn(q.z, q.z));
        float dot = __fmaf_rn(px0, q.x, 0.0f);
        dot = __fmaf_rn(px1, q.y, dot);
        dot = __fmaf_rn(px2, q.z, dot);
        const float d2 = __fsub_rn(__fadd_rn(x2s, qs), __fmul_rn(2.0f, dot));
        return mono(d2);
    };

    // ---- Phase C: exact top-16 SET (mean is order-independent).
    if (S <= 64) {
        const u32 myidx = (lane < S) ? list_s[wv][lane] : 0xFFFFFFFFu;
        const u32 k = (lane < S) ? key32_of(myidx) : 0xFFFFFFFFu;
        const u32 kv = __shfl(sort64_u32(k, lane), 15);

        const bool less = (lane < S) && (k < kv);
        const bool eq   = (lane < S) && (k == kv);
        const int  c_less = __popcll(__ballot(less));
        const int  needed = 16 - c_less;
        const u64  em = __ballot(eq);
        const bool member = less || (eq && (lanes_below(em) < needed));
        const u64  mm = __ballot(member);
        if (member) rank_s[wv][lanes_below(mm)] = myidx;
    } else {
        auto key_of = [&](u32 idx) -> u64 {
            return ((u64)key32_of(idx) << 32) | idx;
        };
        u64 k0 = (lane < S) ? key_of(list_s[wv][lane]) : INF_KEY;
        u64 top = sort64_u64(k0, lane);
        for (int pos = 64; pos < S; pos += 48) {
            const int src = pos + lane - 16;
            const u64 k = (lane < 16) ? top
                                      : ((src < S) ? key_of(list_s[wv][src]) : INF_KEY);
            top = sort64_u64(k, lane);
        }
        if (lane < 16) rank_s[wv][lane] = (u32)top;
    }
    // Same-wave DS producer/consumer: in-order pipe, no barrier needed.

    // ---- Gather + mean, all 64 lanes: rank = lane&15, chunk = lane>>4.
    const int r = lane & 15;
    const int c = lane >> 4;
    const int gidx = (int)rank_s[wv][r];            // winner index, rank r
    const float4 fq = ((const float4*)feat)[(size_t)gidx * 4 + c];
    float f0 = fq.x, f1 = fq.y, f2 = fq.z, f3 = fq.w;
#pragma unroll
    for (int mask = 1; mask <= 8; mask <<= 1) {     // sum over ranks in-group
        f0 = __fadd_rn(f0, __shfl_xor(f0, mask));
        f1 = __fadd_rn(f1, __shfl_xor(f1, mask));
        f2 = __fadd_rn(f2, __shfl_xor(f2, mask));
        f3 = __fadd_rn(f3, __shfl_xor(f3, mask));
    }
    if (r == 0) {
        float4* o4 = (float4*)out + (size_t)i * 4;
        o4[c] = make_float4(__fmul_rn(f0, 0.0625f), __fmul_rn(f1, 0.0625f),
                            __fmul_rn(f2, 0.0625f), __fmul_rn(f3, 0.0625f));
    }
}

extern "C" void kernel_launch(void* const* d_in, const int* in_sizes, int n_in,
                              void* d_out, int out_size, void* d_ws, size_t ws_size,
                              hipStream_t stream) {
    const float* x       = (const float*)d_in[0];
    const float* y       = (const float*)d_in[1];
    const float* feat    = (const float*)d_in[2];
    const int*   x_batch = (const int*)d_in[3];

    const int n   = in_sizes[0] / 3;   // 16384 query points
    const int m   = in_sizes[1] / 3;   // 16384 y points
    const int per = m / 8;             // 2048 per batch (N_BATCHES = 8)

    float* out = (float*)d_out;

    const size_t need = (size_t)m * sizeof(float4);
    const int packed = (ws_size >= need) ? 1 : 0;
    float4* yp = (float4*)d_ws;

    if (packed)
        knn_prep<<<(m + 255) / 256, 256, 0, stream>>>(y, yp, m);

    const int blocks = (n + BLK_WAVES - 1) / BLK_WAVES;   // 2048
    if (packed && per == 2048)
        knn_main<32, 16><<<blocks, THREADS, 0, stream>>>(x, yp, y, feat,
                                                         x_batch, out, n, per, packed);
    else
        knn_main<0, 0><<<blocks, THREADS, 0, stream>>>(x, yp, y, feat,
                                                       x_batch, out, n, per, packed);
}

// Round 19
// 39.351 us; speedup vs baseline: 1.0314x; 1.0314x over previous
//
#include <hip/hip_runtime.h>

// KNN (k=16) within batch-diagonal blocks + neighbor-feature mean-pool.
// N = 16384 points, 8 batches of 2048 (contiguous), FEAT = 16.
//
// R19 = R17 restored verbatim — the measured session best (39.4us).
// R18's conservative-test variant was null-to-worse (survivor-path cost
// offset the scan saving; FETCH/WRITE grew). Session ladder:
//   457 -> 269 -> 99 -> 78.5 -> 84.7 -> 167.9 -> 100 -> 62.7 -> 58.3
//   -> 48.6 -> 41.7 -> 55.2 -> 62.5 -> 53.0 -> 41.6 -> 41.6 -> 39.4 [R17]
//   -> 40.6 [R18 null] -> R17 restored.
//
// Structure: one wave = one point; 32 coalesced float4 loads of packed
// {y,|y|^2}; exact d2 for 16 cached in regs, 16 recomputed (identical
// __f*_rn op sequence => identical bits); thr = 16th-smallest of the 64
// lane-mins (wave bitonic sort-64 on u32 mono keys; >=16 distinct
// candidates <= thr => provably valid); ballot-compacted index append
// (ascending index order); Phase C = exact top-16 SET via u32 key sort +
// stable lowest-index ties (S<=64 fast path; chunked u64 sort fallback);
// all-lane gather + butterfly mean (order relaxation is rounding-only,
// ~1e-6 << 2.2e-2 threshold). Selection is bit-exact vs lax.top_k.

typedef unsigned long long u64;
typedef unsigned int u32;

#define FEAT 16
#define BLK_WAVES 8
#define THREADS (BLK_WAVES * 64)   // 512
#define LIST_CAP 512
#define INF_KEY 0xFFFFFFFFFFFFFFFFull

__global__ void knn_prep(const float* __restrict__ y, float4* __restrict__ yp, int m)
{
    const int j = blockIdx.x * 256 + (int)threadIdx.x;
    if (j < m) {
        const float a0 = y[(size_t)j * 3 + 0];
        const float a1 = y[(size_t)j * 3 + 1];
        const float a2 = y[(size_t)j * 3 + 2];
        const float s  = __fadd_rn(__fadd_rn(__fmul_rn(a0, a0), __fmul_rn(a1, a1)),
                                   __fmul_rn(a2, a2));
        yp[j] = make_float4(a0, a1, a2, s);
    }
}

__device__ __forceinline__ u32 mono(float f) {
    const u32 b = __float_as_uint(f);
    return b ^ (((u32)(((int)b) >> 31)) | 0x80000000u);
}
__device__ __forceinline__ float unmono(u32 h) {
    const u32 b = (h & 0x80000000u) ? (h & 0x7FFFFFFFu) : ~h;
    return __uint_as_float(b);
}
__device__ __forceinline__ int lanes_below(u64 mask) {
    return __builtin_amdgcn_mbcnt_hi((u32)(mask >> 32),
           __builtin_amdgcn_mbcnt_lo((u32)mask, 0));
}

// Cross-lane bitonic sort over the 64 lanes, ascending by lane index.
__device__ __forceinline__ u32 sort64_u32(u32 k, int lane) {
#pragma unroll
    for (int kk = 2; kk <= 64; kk <<= 1) {
#pragma unroll
        for (int j = kk >> 1; j > 0; j >>= 1) {
            const u32 o = __shfl_xor(k, j);
            const bool keep_min = (((lane & j) == 0) == ((lane & kk) == 0));
            const u32 mn = (k < o) ? k : o;
            const u32 mx = (k < o) ? o : k;
            k = keep_min ? mn : mx;
        }
    }
    return k;
}
__device__ __forceinline__ u64 sort64_u64(u64 k, int lane) {
#pragma unroll
    for (int kk = 2; kk <= 64; kk <<= 1) {
#pragma unroll
        for (int j = kk >> 1; j > 0; j >>= 1) {
            const u64 o = __shfl_xor(k, j);
            const bool keep_min = (((lane & j) == 0) == ((lane & kk) == 0));
            const u64 mn = (k < o) ? k : o;
            const u64 mx = (k < o) ? o : k;
            k = keep_min ? mn : mx;
        }
    }
    return k;
}

// REGC: leading iterations with register-cached d2 (FULL static unroll).
// TOTC > 0: compile-time per-lane candidate count. TOTC == 0: fallback.
template <int TOTC, int REGC>
__global__ __launch_bounds__(THREADS, 8) void knn_main(
    const float* __restrict__ x, const float4* __restrict__ yp,
    const float* __restrict__ y, const float* __restrict__ feat,
    const int* __restrict__ x_batch, float* __restrict__ out,
    int n, int per, int packed)
{
    __shared__ u32 list_s[BLK_WAVES][LIST_CAP];  // 16 KiB survivor indices
    __shared__ u32 rank_s[BLK_WAVES][16];        // 512 B winner indices

    const int lane = (int)threadIdx.x & 63;
    const int wv   = (int)(threadIdx.x >> 6);
    const int i    = blockIdx.x * BLK_WAVES + wv;   // this wave's point
    if (i >= n) return;

    const int b     = x_batch[i];                   // lane-uniform
    const int ybase = b * per;

    const float px0 = x[(size_t)i * 3 + 0];
    const float px1 = x[(size_t)i * 3 + 1];
    const float px2 = x[(size_t)i * 3 + 2];
    const float x2s = __fadd_rn(__fadd_rn(__fmul_rn(px0, px0), __fmul_rn(px1, px1)),
                                __fmul_rn(px2, px2));

    float thrf;
    int S = 0;                                      // wave-uniform count

    if constexpr (TOTC > 0) {
        // ---- Phase A: d2 over candidates j = ybase + t*64 + lane.
        float d2c[REGC];
        float md0 = __builtin_inff(), md1 = __builtin_inff();
#pragma unroll
        for (int t = 0; t < REGC; ++t) {
            const float4 q = yp[ybase + t * 64 + lane];   // coalesced
            float dot = __fmaf_rn(px0, q.x, 0.0f);
            dot = __fmaf_rn(px1, q.y, dot);
            dot = __fmaf_rn(px2, q.z, dot);
            const float d2 = __fsub_rn(__fadd_rn(x2s, q.w), __fmul_rn(2.0f, dot));
            d2c[t] = d2;
            if (t & 1) md1 = fminf(md1, d2); else md0 = fminf(md0, d2);
        }
#pragma unroll 4
        for (int t = REGC; t < TOTC; ++t) {
            const float4 q = yp[ybase + t * 64 + lane];
            float dot = __fmaf_rn(px0, q.x, 0.0f);
            dot = __fmaf_rn(px1, q.y, dot);
            dot = __fmaf_rn(px2, q.z, dot);
            const float d2 = __fsub_rn(__fadd_rn(x2s, q.w), __fmul_rn(2.0f, dot));
            if (t & 1) md1 = fminf(md1, d2); else md0 = fminf(md0, d2);
        }
        const float md = fminf(md0, md1);

        // thr = 16th-smallest of the 64 lane-mins (exact d2 bits).
        const u32 sorted = sort64_u32(mono(md), lane);
        thrf = unmono(__shfl(sorted, 15));

        // ---- Phase B: ballot-compacted index append (ascending index order).
#pragma unroll
        for (int t = 0; t < REGC; ++t) {
            const bool pred = (d2c[t] <= thrf);
            const u64 mask = __ballot(pred);
            if (pred) {
                const int slot = S + lanes_below(mask);
                if (slot < LIST_CAP)
                    list_s[wv][slot] = (u32)(ybase + t * 64 + lane);
            }
            S += __popcll(mask);
        }
#pragma unroll 4
        for (int t = REGC; t < TOTC; ++t) {
            const float4 q = yp[ybase + t * 64 + lane];
            float dot = __fmaf_rn(px0, q.x, 0.0f);
            dot = __fmaf_rn(px1, q.y, dot);
            dot = __fmaf_rn(px2, q.z, dot);
            const float d2 = __fsub_rn(__fadd_rn(x2s, q.w), __fmul_rn(2.0f, dot));
            const bool pred = (d2 <= thrf);
            const u64 mask = __ballot(pred);
            if (pred) {
                const int slot = S + lanes_below(mask);
                if (slot < LIST_CAP)
                    list_s[wv][slot] = (u32)(ybase + t * 64 + lane);
            }
            S += __popcll(mask);
        }
    } else {
        // Generic fallback: two-pass scan (R8 structure, unpacked y ok).
        const int iters = per / 64;
        float md = __builtin_inff();
        for (int t = 0; t < iters; ++t) {
            const int j = ybase + t * 64 + lane;
            float q0, q1, q2, qs;
            if (packed) {
                const float4 q = yp[j];
                q0 = q.x; q1 = q.y; q2 = q.z; qs = q.w;
            } else {
                q0 = y[(size_t)j * 3 + 0];
                q1 = y[(size_t)j * 3 + 1];
                q2 = y[(size_t)j * 3 + 2];
                qs = __fadd_rn(__fadd_rn(__fmul_rn(q0, q0), __fmul_rn(q1, q1)),
                               __fmul_rn(q2, q2));
            }
            float dot = __fmaf_rn(px0, q0, 0.0f);
            dot = __fmaf_rn(px1, q1, dot);
            dot = __fmaf_rn(px2, q2, dot);
            md = fminf(md, __fsub_rn(__fadd_rn(x2s, qs), __fmul_rn(2.0f, dot)));
        }
        const u32 sorted = sort64_u32(mono(md), lane);
        thrf = unmono(__shfl(sorted, 15));
        for (int t = 0; t < iters; ++t) {
            const int j = ybase + t * 64 + lane;
            float q0, q1, q2, qs;
            if (packed) {
                const float4 q = yp[j];
                q0 = q.x; q1 = q.y; q2 = q.z; qs = q.w;
            } else {
                q0 = y[(size_t)j * 3 + 0];
                q1 = y[(size_t)j * 3 + 1];
                q2 = y[(size_t)j * 3 + 2];
                qs = __fadd_rn(__fadd_rn(__fmul_rn(q0, q0), __fmul_rn(q1, q1)),
                               __fmul_rn(q2, q2));
            }
            float dot = __fmaf_rn(px0, q0, 0.0f);
            dot = __fmaf_rn(px1, q1, dot);
            dot = __fmaf_rn(px2, q2, dot);
            const float d2 = __fsub_rn(__fadd_rn(x2s, qs), __fmul_rn(2.0f, dot));
            const bool pred = (d2 <= thrf);
            const u64 mask = __ballot(pred);
            if (pred) {
                const int slot = S + lanes_below(mask);
                if (slot < LIST_CAP)
                    list_s[wv][slot] = (u32)j;
            }
            S += __popcll(mask);
        }
    }

    if (S > LIST_CAP) S = LIST_CAP;

    // Recompute a survivor's d2 bits from its index (IDENTICAL op sequence
    // and inputs as phases A/B => identical bits).
    auto key32_of = [&](u32 idx) -> u32 {
        const float4 q = packed ? yp[idx]
                                : make_float4(y[(size_t)idx * 3 + 0],
                                              y[(size_t)idx * 3 + 1],
                                              y[(size_t)idx * 3 + 2], 0.0f);
        float qs;
        if (packed) qs = q.w;
        else        qs = __fadd_rn(__fadd_rn(__fmul_rn(q.x, q.x), __fmul_rn(q.y, q.y)),
                                   __fmul_rn(q.z, q.z));
        float dot = __fmaf_rn(px0, q.x, 0.0f);
        dot = __fmaf_rn(px1, q.y, dot);
        dot = __fmaf_rn(px2, q.z, dot);
        const float d2 = __fsub_rn(__fadd_rn(x2s, qs), __fmul_rn(2.0f, dot));
        return mono(d2);
    };

    // ---- Phase C: exact top-16 SET (mean is order-independent).
    if (S <= 64) {
        // Fast path: u32 key sort -> kv = 16th smallest; membership by
        // (k < kv) plus lowest-index ties (slot order == index order).
        const u32 myidx = (lane < S) ? list_s[wv][lane] : 0xFFFFFFFFu;
        const u32 k = (lane < S) ? key32_of(myidx) : 0xFFFFFFFFu;
        const u32 kv = __shfl(sort64_u32(k, lane), 15);

        const bool less = (lane < S) && (k < kv);
        const bool eq   = (lane < S) && (k == kv);
        const int  c_less = __popcll(__ballot(less));
        const int  needed = 16 - c_less;
        const u64  em = __ballot(eq);
        const bool member = less || (eq && (lanes_below(em) < needed));
        const u64  mm = __ballot(member);
        if (member) rank_s[wv][lanes_below(mm)] = myidx;
    } else {
        // Rare path: chunked wave bitonic sort on u64 (mono<<32|idx) keys.
        auto key_of = [&](u32 idx) -> u64 {
            return ((u64)key32_of(idx) << 32) | idx;
        };
        u64 k0 = (lane < S) ? key_of(list_s[wv][lane]) : INF_KEY;
        u64 top = sort64_u64(k0, lane);
        for (int pos = 64; pos < S; pos += 48) {
            const int src = pos + lane - 16;
            const u64 k = (lane < 16) ? top
                                      : ((src < S) ? key_of(list_s[wv][src]) : INF_KEY);
            top = sort64_u64(k, lane);
        }
        if (lane < 16) rank_s[wv][lane] = (u32)top;
    }
    // Same-wave DS producer/consumer: in-order pipe, no barrier needed.

    // ---- Gather + mean, all 64 lanes: rank = lane&15, chunk = lane>>4.
    const int r = lane & 15;
    const int c = lane >> 4;
    const int gidx = (int)rank_s[wv][r];            // winner index, rank r
    const float4 fq = ((const float4*)feat)[(size_t)gidx * 4 + c];
    float f0 = fq.x, f1 = fq.y, f2 = fq.z, f3 = fq.w;
#pragma unroll
    for (int mask = 1; mask <= 8; mask <<= 1) {     // sum over ranks in-group
        f0 = __fadd_rn(f0, __shfl_xor(f0, mask));
        f1 = __fadd_rn(f1, __shfl_xor(f1, mask));
        f2 = __fadd_rn(f2, __shfl_xor(f2, mask));
        f3 = __fadd_rn(f3, __shfl_xor(f3, mask));
    }
    if (r == 0) {
        float4* o4 = (float4*)out + (size_t)i * 4;
        o4[c] = make_float4(__fmul_rn(f0, 0.0625f), __fmul_rn(f1, 0.0625f),
                            __fmul_rn(f2, 0.0625f), __fmul_rn(f3, 0.0625f));
    }
}

extern "C" void kernel_launch(void* const* d_in, const int* in_sizes, int n_in,
                              void* d_out, int out_size, void* d_ws, size_t ws_size,
                              hipStream_t stream) {
    const float* x       = (const float*)d_in[0];
    const float* y       = (const float*)d_in[1];
    const float* feat    = (const float*)d_in[2];
    const int*   x_batch = (const int*)d_in[3];

    const int n   = in_sizes[0] / 3;   // 16384 query points
    const int m   = in_sizes[1] / 3;   // 16384 y points
    const int per = m / 8;             // 2048 per batch (N_BATCHES = 8)

    float* out = (float*)d_out;

    const size_t need = (size_t)m * sizeof(float4);
    const int packed = (ws_size >= need) ? 1 : 0;
    float4* yp = (float4*)d_ws;

    if (packed)
        knn_prep<<<(m + 255) / 256, 256, 0, stream>>>(y, yp, m);

    const int blocks = (n + BLK_WAVES - 1) / BLK_WAVES;   // 2048
    if (packed && per == 2048)
        knn_main<32, 16><<<blocks, THREADS, 0, stream>>>(x, yp, y, feat,
                                                         x_batch, out, n, per, packed);
    else
        knn_main<0, 0><<<blocks, THREADS, 0, stream>>>(x, yp, y, feat,
                                                       x_batch, out, n, per, packed);
}